// Round 6
// baseline (493.111 us; speedup 1.0000x reference)
//
#include <hip/hip_runtime.h>

#define FUZZ 2187
#define NFEAT 7
#define MID 512
#define NCLS 10
#define BATCH 4096
#define SSTR 2192   // padded row stride for S (21 rows)

constexpr int pw3(int e) { int r = 1; while (e--) r *= 3; return r; }

// ---------------------------------------------------------------------------
// Kernel 1 (atomic-free): S[g=3j+m][n] = sum_{k: digit_j(k)=m} wei[k*7+j, n]
// digit_j(k) = (k / 3^(6-j)) % 3, so k = (hi*3+m)*PL + lo, PL = 3^(6-j),
// hi in [0,3^j), lo in [0,PL). Each (g, n) has exactly ONE writer thread that
// sums its 729 rows -> plain store, no atomics, no S memset. Across the 21
// groups every wei row is read exactly once (134 MB total, same as before).
// Iteration is organized as 27 bursts of 27 fully-unrolled independent loads
// (uniform for every j via compile-time HB/LB/C2 split) -> ~27 loads in
// flight/wave; 735 single-wave blocks = 2.9 blocks/CU -> ~5 MB in flight.
// g==0 blocks also zero K+T/H/v/w (5408 floats; consumed in later dispatches).
// ---------------------------------------------------------------------------
template<int J>
__device__ __forceinline__ float group_sum(const float* __restrict__ wei,
                                           int m, int n) {
    constexpr int PL = pw3(6 - J);                  // lo count
    constexpr int PH = pw3(J);                      // hi count
    constexpr int HB = (PL >= 27) ? 1 : (27 / PL);  // hi per 27-burst
    constexpr int LB = (PL >= 27) ? 27 : PL;        // lo per 27-burst
    constexpr int C2 = (PL >= 27) ? (PL / 27) : 1;  // sub-bursts per hi
    float acc = 0.f;
    for (int h0 = 0; h0 < PH; h0 += HB) {
        for (int c2 = 0; c2 < C2; ++c2) {
            const float* rp = wei +
                (((size_t)(h0 * 3 + m) * PL + (size_t)c2 * 27) * 7 + J) * FUZZ + n;
#pragma unroll
            for (int dh = 0; dh < HB; ++dh)
#pragma unroll
                for (int lo = 0; lo < LB; ++lo)
                    acc += rp[(size_t)(dh * 3 * PL + lo) * (7 * FUZZ)];
        }
    }
    return acc;
}

__global__ __launch_bounds__(64) void k_reduce_wei(const float* __restrict__ wei,
                                                   float* __restrict__ S,
                                                   float* __restrict__ Kz) {
    int g = blockIdx.y;             // 0..20: g = 3*j + m
    if (g == 0) {                   // zero K(5120)+T/H/v/w(288) = 5408 floats
        int tz = blockIdx.x * 64 + threadIdx.x;    // 0..2239
        for (int z = tz; z < NCLS * MID + 288; z += 35 * 64) Kz[z] = 0.f;
    }
    int n = blockIdx.x * 64 + threadIdx.x;
    if (n >= FUZZ) return;
    int j = g / 3, m = g % 3;
    float acc;
    switch (j) {
        case 0: acc = group_sum<0>(wei, m, n); break;
        case 1: acc = group_sum<1>(wei, m, n); break;
        case 2: acc = group_sum<2>(wei, m, n); break;
        case 3: acc = group_sum<3>(wei, m, n); break;
        case 4: acc = group_sum<4>(wei, m, n); break;
        case 5: acc = group_sum<5>(wei, m, n); break;
        default: acc = group_sum<6>(wei, m, n); break;
    }
    S[g * SSTR + n] = acc;
}

__device__ __forceinline__ float wave_sum(float v) {
#pragma unroll
    for (int off = 32; off > 0; off >>= 1) v += __shfl_down(v, off, 64);
    return v;
}

// ---------------------------------------------------------------------------
// Kernel 2 (mixed roles by blockIdx.x):
//   gid in [0,512):      SW1[t][i=gid] = sum_n S[t,n]*W1[i,n]; ws1[i]
//                        (4-wave block, LDS reduce) — unchanged, verified.
//   gid in [512,512+270): K partials. idx=(gid-512): c=idx/27, n-chunk of 81.
//                        Thread tid owns i=tid and i=tid+256; atomicAdd into
//                        K (zeroed by k_reduce_wei's g==0 blocks).
// K = W3*W2 (10x512): G*W3^T == SW1*K^T, eliminating the old k_g dispatch.
// ---------------------------------------------------------------------------
__global__ __launch_bounds__(256) void k_sw1(const float* __restrict__ S,
                                             const float* __restrict__ W1,
                                             const float* __restrict__ W2,
                                             const float* __restrict__ W3,
                                             float* __restrict__ SW1,
                                             float* __restrict__ ws1,
                                             float* __restrict__ K) {
    int gid = blockIdx.x;
    int tid = threadIdx.x;
    if (gid >= MID) {
        int idx = gid - MID;        // 0..269
        int c = idx / 27;
        int chunk = idx % 27;
        int n0 = chunk * 81;
        float acc0 = 0.f, acc1 = 0.f;
        const float* w3row = W3 + (size_t)c * FUZZ;
        const float* w2col = W2 + tid;
#pragma unroll 9
        for (int n = n0; n < n0 + 81; ++n) {
            float w3 = w3row[n];
            acc0 += w3 * w2col[(size_t)n * MID];
            acc1 += w3 * w2col[(size_t)n * MID + 256];
        }
        atomicAdd(&K[c * MID + tid],       acc0);
        atomicAdd(&K[c * MID + tid + 256], acc1);
        return;
    }
    int i = gid;
    float acc[21];
    float aw = 0.f;
#pragma unroll
    for (int t = 0; t < 21; ++t) acc[t] = 0.f;
    const float* w1row = W1 + (size_t)i * FUZZ;
    for (int n = tid; n < FUZZ; n += 256) {
        float w1 = w1row[n];
        aw += w1;
#pragma unroll
        for (int t = 0; t < 21; ++t) acc[t] += S[t * SSTR + n] * w1;
    }
#pragma unroll
    for (int t = 0; t < 21; ++t) acc[t] = wave_sum(acc[t]);
    aw = wave_sum(aw);
    __shared__ float red[4][22];
    int w = tid >> 6, lane = tid & 63;
    if (lane == 0) {
#pragma unroll
        for (int t = 0; t < 21; ++t) red[w][t] = acc[t];
        red[w][21] = aw;
    }
    __syncthreads();
    if (tid < 22) {
        float s = red[0][tid] + red[1][tid] + red[2][tid] + red[3][tid];
        if (tid < 21) SW1[tid * MID + i] = s;
        else          ws1[i] = s;
    }
}

// ---------------------------------------------------------------------------
// Kernel 3: H[jm][c] = sum_n S[jm,n]*W3[c,n] + sum_i SW1[jm,i]*K[c,i]
//           v[c] = sum_n W3[c,n] + sum_i ws1[i]*K[c,i]
//           w[c] = sum_i b1[i]*K[c,i] + sum_n b2[n]*W3[c,n] + b3[c]
//           T[jm] = sum_n S[jm,n]               (blockIdx.x == 10)
// Grid (11, 9): n split into 9 chunks of 243; chunks 0..7 additionally own
// i = chunk*64+lane (one i per lane, covers all 512). atomicAdd epilogue
// into T/H/v/w (zeroed by k_reduce_wei).
// ---------------------------------------------------------------------------
__global__ __launch_bounds__(64) void k_h(const float* __restrict__ S,
                                          const float* __restrict__ SW1,
                                          const float* __restrict__ ws1,
                                          const float* __restrict__ K,
                                          const float* __restrict__ b1,
                                          const float* __restrict__ b2,
                                          const float* __restrict__ b3,
                                          const float* __restrict__ W3,
                                          float* __restrict__ H,
                                          float* __restrict__ v,
                                          float* __restrict__ w,
                                          float* __restrict__ T) {
    int c = blockIdx.x;
    int chunk = blockIdx.y;
    int lane = threadIdx.x;
    int n0 = chunk * 243;
    if (c < NCLS) {
        float acc[21];
        float av = 0.f, aw = 0.f;
#pragma unroll
        for (int t = 0; t < 21; ++t) acc[t] = 0.f;
        const float* w3row = W3 + (size_t)c * FUZZ;
        for (int n = n0 + lane; n < n0 + 243; n += 64) {
            float w3 = w3row[n];
            av += w3;
            aw += b2[n] * w3;
#pragma unroll
            for (int t = 0; t < 21; ++t)
                acc[t] += S[t * SSTR + n] * w3;
        }
        if (chunk < 8) {
            int i = chunk * 64 + lane;      // each lane exactly one i
            float kk = K[c * MID + i];
            av += ws1[i] * kk;
            aw += b1[i] * kk;
#pragma unroll
            for (int t = 0; t < 21; ++t)
                acc[t] += SW1[t * MID + i] * kk;
        }
#pragma unroll
        for (int t = 0; t < 21; ++t) acc[t] = wave_sum(acc[t]);
        av = wave_sum(av);
        aw = wave_sum(aw);
        if (lane == 0) {
#pragma unroll
            for (int t = 0; t < 21; ++t) atomicAdd(&H[t * NCLS + c], acc[t]);
            atomicAdd(&v[c], av);
            atomicAdd(&w[c], aw + (chunk == 0 ? b3[c] : 0.f));
        }
    } else {
        float acc[21];
#pragma unroll
        for (int t = 0; t < 21; ++t) acc[t] = 0.f;
        for (int n = n0 + lane; n < n0 + 243; n += 64) {
#pragma unroll
            for (int t = 0; t < 21; ++t) acc[t] += S[t * SSTR + n];
        }
#pragma unroll
        for (int t = 0; t < 21; ++t) acc[t] = wave_sum(acc[t]);
        if (lane == 0) {
#pragma unroll
            for (int t = 0; t < 21; ++t) atomicAdd(&T[t], acc[t]);
        }
    }
}

// ---------------------------------------------------------------------------
// Kernel 4: per-batch epilogue. 64 blocks x 64 threads spreads across CUs.
// ---------------------------------------------------------------------------
__global__ __launch_bounds__(64) void k_out(const float* __restrict__ x,
                                            const float* __restrict__ cc,
                                            const float* __restrict__ bbv,
                                            const float* __restrict__ bais,
                                            const float* __restrict__ T,
                                            const float* __restrict__ H,
                                            const float* __restrict__ v,
                                            const float* __restrict__ w,
                                            float* __restrict__ out) {
    int b = blockIdx.x * 64 + threadIdx.x;
    if (b >= BATCH) return;
    float xv[NFEAT];
#pragma unroll
    for (int j = 0; j < NFEAT; ++j) xv[j] = x[b * NFEAT + j];
    float u[21];
#pragma unroll
    for (int j = 0; j < NFEAT; ++j) {
#pragma unroll
        for (int m = 0; m < 3; ++m) {
            float d = xv[j] - cc[j * 3 + m];
            float bv = bbv[j * 3 + m];
            u[j * 3 + m] = expf(-(d * d) / (bv * bv));
        }
    }
    float ba = bais[0];
    float r = 2187.0f * ba;
#pragma unroll
    for (int t = 0; t < 21; ++t) r += u[t] * T[t];
    float inv = 1.0f / r;
#pragma unroll
    for (int c = 0; c < NCLS; ++c) {
        float s = 0.f;
#pragma unroll
        for (int t = 0; t < 21; ++t) s += u[t] * H[t * NCLS + c];
        float h = (s + ba * v[c]) * inv + w[c];
        out[b * NCLS + c] = (h >= 0.f) ? h : 0.2f * h;
    }
}

extern "C" void kernel_launch(void* const* d_in, const int* in_sizes, int n_in,
                              void* d_out, int out_size, void* d_ws, size_t ws_size,
                              hipStream_t stream) {
    const float* x    = (const float*)d_in[0];
    const float* c    = (const float*)d_in[1];
    const float* bbv  = (const float*)d_in[2];
    const float* wei  = (const float*)d_in[3];
    const float* bais = (const float*)d_in[4];
    const float* W1   = (const float*)d_in[5];
    const float* b1   = (const float*)d_in[6];
    const float* W2   = (const float*)d_in[7];
    const float* b2   = (const float*)d_in[8];
    const float* W3   = (const float*)d_in[9];
    const float* b3   = (const float*)d_in[10];

    // K and T/H/v/w contiguous: zeroed by k_reduce_wei's g==0 blocks.
    float* ws  = (float*)d_ws;
    float* S   = ws;                         // 21*SSTR (fully overwritten)
    float* K   = S + 21 * SSTR;              // 10*512
    float* T   = K + NCLS * MID;             // 32
    float* H   = T + 32;                     // 224 (21*10 used)
    float* v   = H + 224;                    // 16
    float* w   = v + 16;                     // 16   (T..w = 288)
    float* SW1 = w + 16;                     // 21*512
    float* ws1 = SW1 + 21 * MID;             // 512

    k_reduce_wei<<<dim3(35, 21), 64, 0, stream>>>(wei, S, K);
    k_sw1<<<MID + 270, 256, 0, stream>>>(S, W1, W2, W3, SW1, ws1, K);
    k_h<<<dim3(NCLS + 1, 9), 64, 0, stream>>>(S, SW1, ws1, K, b1, b2, b3, W3,
                                              H, v, w, T);
    k_out<<<(BATCH + 63) / 64, 64, 0, stream>>>(x, c, bbv, bais, T, H, v, w,
                                                (float*)d_out);
}

// Round 7
// 249.155 us; speedup vs baseline: 1.9791x; 1.9791x over previous
//
#include <hip/hip_runtime.h>

#define FUZZ 2187
#define NFEAT 7
#define MID 512
#define NCLS 10
#define BATCH 4096
#define SSTR 2192   // padded row stride for S (21 rows)

// ---------------------------------------------------------------------------
// Kernel 1: S[jm][n] = sum over k with IDX[k,j]==m of wei[k*7+j, n]
// k = by*9 + kk, by in [0,243): digits d0..d4 block-uniform (5 register
// accumulators, row picked once at the end); kk in [0,9): d5 = kk/3 = burst
// index, d6 = kk%3 compile-time accumulator targets. 11 atomics/thread.
// Grid (9, 243) = 8748 waves = 34/CU.
// MLP: loads are BURST-LOADED 21-at-a-time into named registers, THEN
// accumulated — forces ~21 outstanding loads/wave (round-5's load-then-add
// pattern let the compiler keep only ~2-3 in flight -> ~2.3 TB/s; round-6's
// 735-wave variant was worse, 333 GB/s. Need ~22 KB/CU in flight for 6 TB/s).
// ---------------------------------------------------------------------------
__global__ __launch_bounds__(256) void k_reduce_wei(const float* __restrict__ wei,
                                                    float* __restrict__ S) {
    int n = blockIdx.x * 256 + threadIdx.x;
    if (n >= FUZZ) return;
    int by = blockIdx.y;            // top 5 base-3 digits of k
    int t = by;
    int d4 = t % 3; t /= 3;
    int d3 = t % 3; t /= 3;
    int d2 = t % 3; t /= 3;
    int d1 = t % 3; t /= 3;
    int d0 = t;                     // by < 243
    float a0 = 0.f, a1 = 0.f, a2 = 0.f, a3 = 0.f, a4 = 0.f;
    float h5[3] = {0.f, 0.f, 0.f};
    float h6[3] = {0.f, 0.f, 0.f};
    const float* base = wei + (size_t)(by * 63) * FUZZ + n;
#pragma unroll
    for (int kb = 0; kb < 3; ++kb) {          // burst = 3 kk = 21 loads
        float v[21];
#pragma unroll
        for (int ki = 0; ki < 3; ++ki)
#pragma unroll
            for (int jj = 0; jj < 7; ++jj)
                v[ki * 7 + jj] =
                    base[(size_t)(((kb * 3 + ki) * 7) + jj) * FUZZ];
        // accumulate after the whole burst is issued
#pragma unroll
        for (int ki = 0; ki < 3; ++ki) {
            a0 += v[ki * 7 + 0];
            a1 += v[ki * 7 + 1];
            a2 += v[ki * 7 + 2];
            a3 += v[ki * 7 + 3];
            a4 += v[ki * 7 + 4];
            h5[kb] += v[ki * 7 + 5];          // d5 = (kb*3+ki)/3 = kb
            h6[ki] += v[ki * 7 + 6];          // d6 = (kb*3+ki)%3 = ki
        }
    }
    atomicAdd(&S[(0  + d0) * SSTR + n], a0);
    atomicAdd(&S[(3  + d1) * SSTR + n], a1);
    atomicAdd(&S[(6  + d2) * SSTR + n], a2);
    atomicAdd(&S[(9  + d3) * SSTR + n], a3);
    atomicAdd(&S[(12 + d4) * SSTR + n], a4);
#pragma unroll
    for (int m = 0; m < 3; ++m) {
        atomicAdd(&S[(15 + m) * SSTR + n], h5[m]);
        atomicAdd(&S[(18 + m) * SSTR + n], h6[m]);
    }
}

__device__ __forceinline__ float wave_sum(float v) {
#pragma unroll
    for (int off = 32; off > 0; off >>= 1) v += __shfl_down(v, off, 64);
    return v;
}

// ---------------------------------------------------------------------------
// Kernel 2 (mixed roles by blockIdx.x):
//   gid in [0,512):      SW1[t][i=gid] = sum_n S[t,n]*W1[i,n]; ws1[i]
//                        (4-wave block, LDS reduce) — unchanged, verified.
//   gid in [512,512+270): K partials. idx=(gid-512): c=idx/27, n-chunk of 81.
//                        Thread tid owns i=tid and i=tid+256; atomicAdd into
//                        K (zeroed by the up-front memset).
// K = W3*W2 (10x512): G*W3^T == SW1*K^T, eliminating the old k_g dispatch.
// ---------------------------------------------------------------------------
__global__ __launch_bounds__(256) void k_sw1(const float* __restrict__ S,
                                             const float* __restrict__ W1,
                                             const float* __restrict__ W2,
                                             const float* __restrict__ W3,
                                             float* __restrict__ SW1,
                                             float* __restrict__ ws1,
                                             float* __restrict__ K) {
    int gid = blockIdx.x;
    int tid = threadIdx.x;
    if (gid >= MID) {
        int idx = gid - MID;        // 0..269
        int c = idx / 27;
        int chunk = idx % 27;
        int n0 = chunk * 81;
        float acc0 = 0.f, acc1 = 0.f;
        const float* w3row = W3 + (size_t)c * FUZZ;
        const float* w2col = W2 + tid;
#pragma unroll 9
        for (int n = n0; n < n0 + 81; ++n) {
            float w3 = w3row[n];
            acc0 += w3 * w2col[(size_t)n * MID];
            acc1 += w3 * w2col[(size_t)n * MID + 256];
        }
        atomicAdd(&K[c * MID + tid],       acc0);
        atomicAdd(&K[c * MID + tid + 256], acc1);
        return;
    }
    int i = gid;
    float acc[21];
    float aw = 0.f;
#pragma unroll
    for (int t = 0; t < 21; ++t) acc[t] = 0.f;
    const float* w1row = W1 + (size_t)i * FUZZ;
    for (int n = tid; n < FUZZ; n += 256) {
        float w1 = w1row[n];
        aw += w1;
#pragma unroll
        for (int t = 0; t < 21; ++t) acc[t] += S[t * SSTR + n] * w1;
    }
#pragma unroll
    for (int t = 0; t < 21; ++t) acc[t] = wave_sum(acc[t]);
    aw = wave_sum(aw);
    __shared__ float red[4][22];
    int w = tid >> 6, lane = tid & 63;
    if (lane == 0) {
#pragma unroll
        for (int t = 0; t < 21; ++t) red[w][t] = acc[t];
        red[w][21] = aw;
    }
    __syncthreads();
    if (tid < 22) {
        float s = red[0][tid] + red[1][tid] + red[2][tid] + red[3][tid];
        if (tid < 21) SW1[tid * MID + i] = s;
        else          ws1[i] = s;
    }
}

// ---------------------------------------------------------------------------
// Kernel 3: H[jm][c] = sum_n S[jm,n]*W3[c,n] + sum_i SW1[jm,i]*K[c,i]
//           v[c] = sum_n W3[c,n] + sum_i ws1[i]*K[c,i]
//           w[c] = sum_i b1[i]*K[c,i] + sum_n b2[n]*W3[c,n] + b3[c]
//           T[jm] = sum_n S[jm,n]               (blockIdx.x == 10)
// Grid (11, 9): n split into 9 chunks of 243; chunks 0..7 additionally own
// i = chunk*64+lane (one i per lane, covers all 512). atomicAdd epilogue
// into T/H/v/w (zeroed by the up-front memset).
// ---------------------------------------------------------------------------
__global__ __launch_bounds__(64) void k_h(const float* __restrict__ S,
                                          const float* __restrict__ SW1,
                                          const float* __restrict__ ws1,
                                          const float* __restrict__ K,
                                          const float* __restrict__ b1,
                                          const float* __restrict__ b2,
                                          const float* __restrict__ b3,
                                          const float* __restrict__ W3,
                                          float* __restrict__ H,
                                          float* __restrict__ v,
                                          float* __restrict__ w,
                                          float* __restrict__ T) {
    int c = blockIdx.x;
    int chunk = blockIdx.y;
    int lane = threadIdx.x;
    int n0 = chunk * 243;
    if (c < NCLS) {
        float acc[21];
        float av = 0.f, aw = 0.f;
#pragma unroll
        for (int t = 0; t < 21; ++t) acc[t] = 0.f;
        const float* w3row = W3 + (size_t)c * FUZZ;
        for (int n = n0 + lane; n < n0 + 243; n += 64) {
            float w3 = w3row[n];
            av += w3;
            aw += b2[n] * w3;
#pragma unroll
            for (int t = 0; t < 21; ++t)
                acc[t] += S[t * SSTR + n] * w3;
        }
        if (chunk < 8) {
            int i = chunk * 64 + lane;      // each lane exactly one i
            float kk = K[c * MID + i];
            av += ws1[i] * kk;
            aw += b1[i] * kk;
#pragma unroll
            for (int t = 0; t < 21; ++t)
                acc[t] += SW1[t * MID + i] * kk;
        }
#pragma unroll
        for (int t = 0; t < 21; ++t) acc[t] = wave_sum(acc[t]);
        av = wave_sum(av);
        aw = wave_sum(aw);
        if (lane == 0) {
#pragma unroll
            for (int t = 0; t < 21; ++t) atomicAdd(&H[t * NCLS + c], acc[t]);
            atomicAdd(&v[c], av);
            atomicAdd(&w[c], aw + (chunk == 0 ? b3[c] : 0.f));
        }
    } else {
        float acc[21];
#pragma unroll
        for (int t = 0; t < 21; ++t) acc[t] = 0.f;
        for (int n = n0 + lane; n < n0 + 243; n += 64) {
#pragma unroll
            for (int t = 0; t < 21; ++t) acc[t] += S[t * SSTR + n];
        }
#pragma unroll
        for (int t = 0; t < 21; ++t) acc[t] = wave_sum(acc[t]);
        if (lane == 0) {
#pragma unroll
            for (int t = 0; t < 21; ++t) atomicAdd(&T[t], acc[t]);
        }
    }
}

// ---------------------------------------------------------------------------
// Kernel 4: per-batch epilogue. 64 blocks x 64 threads spreads across CUs.
// ---------------------------------------------------------------------------
__global__ __launch_bounds__(64) void k_out(const float* __restrict__ x,
                                            const float* __restrict__ cc,
                                            const float* __restrict__ bbv,
                                            const float* __restrict__ bais,
                                            const float* __restrict__ T,
                                            const float* __restrict__ H,
                                            const float* __restrict__ v,
                                            const float* __restrict__ w,
                                            float* __restrict__ out) {
    int b = blockIdx.x * 64 + threadIdx.x;
    if (b >= BATCH) return;
    float xv[NFEAT];
#pragma unroll
    for (int j = 0; j < NFEAT; ++j) xv[j] = x[b * NFEAT + j];
    float u[21];
#pragma unroll
    for (int j = 0; j < NFEAT; ++j) {
#pragma unroll
        for (int m = 0; m < 3; ++m) {
            float d = xv[j] - cc[j * 3 + m];
            float bv = bbv[j * 3 + m];
            u[j * 3 + m] = expf(-(d * d) / (bv * bv));
        }
    }
    float ba = bais[0];
    float r = 2187.0f * ba;
#pragma unroll
    for (int t = 0; t < 21; ++t) r += u[t] * T[t];
    float inv = 1.0f / r;
#pragma unroll
    for (int c = 0; c < NCLS; ++c) {
        float s = 0.f;
#pragma unroll
        for (int t = 0; t < 21; ++t) s += u[t] * H[t * NCLS + c];
        float h = (s + ba * v[c]) * inv + w[c];
        out[b * NCLS + c] = (h >= 0.f) ? h : 0.2f * h;
    }
}

extern "C" void kernel_launch(void* const* d_in, const int* in_sizes, int n_in,
                              void* d_out, int out_size, void* d_ws, size_t ws_size,
                              hipStream_t stream) {
    const float* x    = (const float*)d_in[0];
    const float* c    = (const float*)d_in[1];
    const float* bbv  = (const float*)d_in[2];
    const float* wei  = (const float*)d_in[3];
    const float* bais = (const float*)d_in[4];
    const float* W1   = (const float*)d_in[5];
    const float* b1   = (const float*)d_in[6];
    const float* W2   = (const float*)d_in[7];
    const float* b2   = (const float*)d_in[8];
    const float* W3   = (const float*)d_in[9];
    const float* b3   = (const float*)d_in[10];

    // S, K, T/H/v/w contiguous so ONE memset zeroes everything atomics need.
    float* ws  = (float*)d_ws;
    float* S   = ws;                         // 21*SSTR           = 46032
    float* K   = S + 21 * SSTR;              // 10*512            = 5120
    float* T   = K + NCLS * MID;             // 32
    float* H   = T + 32;                     // 224 (21*10 used)
    float* v   = H + 224;                    // 16
    float* w   = v + 16;                     // 16   (T..w = 288)
    float* SW1 = w + 16;                     // 21*512
    float* ws1 = SW1 + 21 * MID;             // 512

    hipMemsetAsync(S, 0, (size_t)(21 * SSTR + NCLS * MID + 288) * sizeof(float),
                   stream);
    k_reduce_wei<<<dim3(9, 243), 256, 0, stream>>>(wei, S);
    k_sw1<<<MID + 270, 256, 0, stream>>>(S, W1, W2, W3, SW1, ws1, K);
    k_h<<<dim3(NCLS + 1, 9), 64, 0, stream>>>(S, SW1, ws1, K, b1, b2, b3, W3,
                                              H, v, w, T);
    k_out<<<(BATCH + 63) / 64, 64, 0, stream>>>(x, c, bbv, bais, T, H, v, w,
                                                (float*)d_out);
}